// Round 14
// baseline (339.587 us; speedup 1.0000x reference)
//
#include <hip/hip_runtime.h>
#include <math.h>

// CausalSelfAttention w/ KV cache, MI355X gfx950.
// B=8 T=64 C=2048 H=16 hd=128 S=4096 -> SKV=4160. All device I/O is FLOAT32.
// Internals: bf16 MFMA (16x16x32), f32 accumulate.
// R13: WAVE-SPECIALIZED attn (producer-consumer). Waves 0-1 = loaders:
// stream K/V tiles (2 reg sets, loads-before-stores), write bf16 into
// double-buffered LDS + f32 cache-copy stores; they never sit in the compute
// chain. Waves 2-3 = computers (32 q each): QK/softmax/PV from LDS only.
// ONE lgkm-only barrier per tile (dbuf handoff). 3 blocks/CU.
// gemm = R5 depth-1 (best-known 344 config). nseg=13.

typedef __attribute__((ext_vector_type(4))) float f32x4;
typedef __attribute__((ext_vector_type(8))) short s16x8;
typedef __attribute__((ext_vector_type(4))) short s16x4;
typedef __attribute__((ext_vector_type(2))) unsigned int u32x2;
typedef __attribute__((ext_vector_type(4))) unsigned int u32x4;

#define MFMA_BF16(A_, B_, C_) __builtin_amdgcn_mfma_f32_16x16x32_bf16((A_), (B_), (C_), 0, 0, 0)

__device__ __forceinline__ unsigned short f2bf(float f) {
  unsigned int u = __builtin_bit_cast(unsigned int, f);
  u += 0x7FFFu + ((u >> 16) & 1u);
  return (unsigned short)(u >> 16);
}
__device__ __forceinline__ unsigned int pack2(float a, float b) {
  return (unsigned int)f2bf(a) | ((unsigned int)f2bf(b) << 16);
}
// Barrier with LDS-visibility only: does NOT drain vmcnt (loader stores/loads
// stay in flight across tiles).
__device__ __forceinline__ void lds_barrier() {
  asm volatile("s_waitcnt lgkmcnt(0)" ::: "memory");
  __builtin_amdgcn_s_barrier();
}

// ---------------------------------------------------------------------------
// GEMM (R5 depth-1, best-known). BM x 128 tile, 4 waves (2x2), k-step 64.
// mode 0 (qkv, BM=64): n<2048 -> qws (bf16*QSCALE, [B,H,T,hd]); 2048..4095 ->
// kout tail rows 4096..4159; >=4096 -> vout tail. mode 1 (proj, BM=32).
// ---------------------------------------------------------------------------
constexpr float QSCALE = 0.08838834764831845f * 1.4426950408889634f; // 1/sqrt(128)*log2e

template <int BM>
__global__ __launch_bounds__(256) void gemm_kernel(
    const float* __restrict__ A, const float* __restrict__ W,
    int ncols, int mode,
    unsigned short* __restrict__ qws, float* __restrict__ kout,
    float* __restrict__ vout, float* __restrict__ yout)
{
  constexpr int MI = BM / 32;
  constexpr int AIT = BM / 32;
  __shared__ __align__(16) unsigned short Alds[BM][72];
  __shared__ __align__(16) unsigned short Blds[128][72];

  const int tid = threadIdx.x;
  const int w = tid >> 6, l = tid & 63;
  const int lr = l & 15, lg = l >> 4;
  const int n0 = blockIdx.x * 128;
  const int m0 = blockIdx.y * BM;
  const int wm = (w >> 1) * (BM / 2), wn = (w & 1) * 64;

  const int arow = tid >> 3, acol = (tid & 7) << 3;
  const int bkp = tid >> 4, bcol = (tid & 15) << 3;
  const int bswz = ((bcol >> 3) & 7) << 3;

  f32x4 ar[AIT][2];
  f32x4 br[2][4];

  auto loadA = [&](int k0) {
#pragma unroll
    for (int it = 0; it < AIT; ++it) {
      const float* pa = A + (size_t)(m0 + it * 32 + arow) * 2048 + k0 + acol;
      ar[it][0] = *(const f32x4*)pa;
      ar[it][1] = *(const f32x4*)(pa + 4);
    }
  };
  auto loadB = [&](int k0) {
#pragma unroll
    for (int i = 0; i < 2; ++i) {
      const int krow = 2 * (i * 16 + bkp);
      const float* pw = W + (size_t)(k0 + krow) * ncols + n0 + bcol;
      br[i][0] = *(const f32x4*)pw;
      br[i][1] = *(const f32x4*)(pw + 4);
      br[i][2] = *(const f32x4*)(pw + ncols);
      br[i][3] = *(const f32x4*)(pw + ncols + 4);
    }
  };

  f32x4 acc[MI][4] = {};

  loadA(0); loadB(0);
  for (int ks = 0; ks < 32; ++ks) {
#pragma unroll
    for (int it = 0; it < AIT; ++it) {
      u32x4 p;
      p[0] = pack2(ar[it][0][0], ar[it][0][1]); p[1] = pack2(ar[it][0][2], ar[it][0][3]);
      p[2] = pack2(ar[it][1][0], ar[it][1][1]); p[3] = pack2(ar[it][1][2], ar[it][1][3]);
      *(u32x4*)(&Alds[it * 32 + arow][acol]) = p;
    }
#pragma unroll
    for (int i = 0; i < 2; ++i) {
      const int krow = 2 * (i * 16 + bkp);
      const int kc = krow ^ bswz;
#pragma unroll
      for (int j = 0; j < 8; ++j) {
        const float v0 = (j < 4) ? br[i][0][j] : br[i][1][j - 4];
        const float v1 = (j < 4) ? br[i][2][j] : br[i][3][j - 4];
        *(unsigned int*)(&Blds[bcol + j][kc]) = pack2(v0, v1);
      }
    }
    lds_barrier();

    if (ks < 31) { loadA((ks + 1) * 64); loadB((ks + 1) * 64); }

    s16x8 af[MI][2], bfr[4][2];
#pragma unroll
    for (int mi = 0; mi < MI; ++mi)
#pragma unroll
      for (int kk = 0; kk < 2; ++kk)
        af[mi][kk] = *(const s16x8*)(&Alds[wm + mi * 16 + lr][kk * 32 + lg * 8]);
#pragma unroll
    for (int ni = 0; ni < 4; ++ni) {
      const int n = wn + ni * 16 + lr;
      const int nswz = ((n >> 3) & 7) << 3;
#pragma unroll
      for (int kk = 0; kk < 2; ++kk)
        bfr[ni][kk] = *(const s16x8*)(&Blds[n][(kk * 32 + lg * 8) ^ nswz]);
    }
#pragma unroll
    for (int kk = 0; kk < 2; ++kk)
#pragma unroll
      for (int mi = 0; mi < MI; ++mi)
#pragma unroll
        for (int ni = 0; ni < 4; ++ni)
          acc[mi][ni] = MFMA_BF16(af[mi][kk], bfr[ni][kk], acc[mi][ni]);
    lds_barrier();
  }

  if (mode == 0) {
    const int which = n0 >> 11;
    const int h = (n0 >> 7) & 15;
    float* kv = (which == 1) ? kout : vout;
#pragma unroll
    for (int mi = 0; mi < MI; ++mi)
#pragma unroll
      for (int ni = 0; ni < 4; ++ni) {
        const int d = wn + ni * 16 + lr;
#pragma unroll
        for (int r = 0; r < 4; ++r) {
          const int mg = m0 + wm + mi * 16 + lg * 4 + r;
          const int b = mg >> 6, t = mg & 63;
          const float val = acc[mi][ni][r];
          if (which == 0)
            qws[(((size_t)(b * 16 + h) * 64 + t) << 7) + d] = f2bf(val * QSCALE);
          else
            kv[((size_t)(b * 16 + h) * 4160 + 4096 + t) * 128 + d] = val;
        }
      }
  } else {
#pragma unroll
    for (int mi = 0; mi < MI; ++mi)
#pragma unroll
      for (int ni = 0; ni < 4; ++ni) {
        const int n = n0 + wn + ni * 16 + lr;
#pragma unroll
        for (int r = 0; r < 4; ++r) {
          const int mg = m0 + wm + mi * 16 + lg * 4 + r;
          yout[(size_t)mg * 2048 + n] = acc[mi][ni][r];
        }
      }
  }
}

// ---------------------------------------------------------------------------
// Wave-specialized fused cache-copy + flash attention.
// Waves 0-1: loaders (128 threads): thread owns key-row skr=tid>>2, float cols
//   sd+16c (64B/row/instr coalesced). 2 reg sets; per tile: issue loads(t+1)
//   FIRST, then copy-stores(t), then convert(t+1)->LDS (counted vmcnt).
// Waves 2-3: computers, 32 q-rows each, LDS-only inner loop.
// LDS (dbuf): K[2][32][128] full-row-XOR; VT[2][128][40]; P[2 cw][32][40].
// One lds_barrier per tile. ntiles must be EVEN (130/26/10 all even).
// ---------------------------------------------------------------------------
__global__ __launch_bounds__(256) void attn_kernel(
    const float* __restrict__ pastk, const float* __restrict__ pastv,
    const unsigned short* __restrict__ qws,
    float* __restrict__ kout, float* __restrict__ vout,
    float* __restrict__ Ows, float* __restrict__ mlws,
    int nseg, int seglen, int ntiles)
{
  __shared__ __align__(16) unsigned short Klds[2][32 * 128];
  __shared__ __align__(16) unsigned short VT[2][128 * 40];
  __shared__ __align__(16) unsigned short Plds[2][32 * 40];

  const int tid = threadIdx.x;
  const int w = tid >> 6, l = tid & 63;
  const int lr = l & 15, lg = l >> 4;
  const int bh = blockIdx.x / nseg;
  const int seg = blockIdx.x % nseg;
  const int segbase = seg * seglen;

  if (w < 2) {
    // ============================ LOADER ============================
    const int skr = tid >> 2;          // key row 0..31
    const int sd = (tid & 3) << 2;     // float col start 0,4,8,12
    const int kswz = (skr & 7) << 4;   // full-row XOR (ushort units)

    f32x4 kvA[8], vvA[8], kvB[8], vvB[8];
    int sA = 0, sB = 0; size_t oA = 0, oB = 0;

    auto load_tile = [&](int t, f32x4 (&kv)[8], f32x4 (&vv)[8], int& sr, size_t& oor) {
      const int s = segbase + t * 32 + skr;
      const size_t oo = ((size_t)bh * 4160 + s) * 128 + sd;
      sr = s; oor = oo;
      if (s < 4096) {
        const float* a = pastk + ((size_t)bh * 4096 + s) * 128 + sd;
        const float* b = pastv + ((size_t)bh * 4096 + s) * 128 + sd;
#pragma unroll
        for (int c = 0; c < 8; ++c) { kv[c] = *(const f32x4*)(a + 16 * c); vv[c] = *(const f32x4*)(b + 16 * c); }
      } else {
#pragma unroll
        for (int c = 0; c < 8; ++c) { kv[c] = *(const f32x4*)(kout + oo + 16 * c); vv[c] = *(const f32x4*)(vout + oo + 16 * c); }
      }
    };
    auto store_tile = [&](const f32x4 (&kv)[8], const f32x4 (&vv)[8], int sr, size_t oo) {
      if (sr < 4096) {
        float* ko = kout + oo; float* vo = vout + oo;
#pragma unroll
        for (int c = 0; c < 8; ++c) { *(f32x4*)(ko + 16 * c) = kv[c]; *(f32x4*)(vo + 16 * c) = vv[c]; }
      }
    };
    auto convert_tile = [&](const f32x4 (&kv)[8], const f32x4 (&vv)[8], int buf) {
      unsigned short* Kb = Klds[buf];
      unsigned short* Vb = VT[buf];
#pragma unroll
      for (int c = 0; c < 8; ++c) {
        const int d0 = sd + 16 * c;
        u32x2 pk;
        pk[0] = pack2(kv[c][0], kv[c][1]);
        pk[1] = pack2(kv[c][2], kv[c][3]);
        *(u32x2*)(&Kb[skr * 128 + (d0 ^ kswz)]) = pk;
#pragma unroll
        for (int e = 0; e < 4; ++e)
          Vb[(d0 + e) * 40 + skr] = f2bf(vv[c][e]);
      }
    };

    load_tile(0, kvA, vvA, sA, oA);
    convert_tile(kvA, vvA, 0);
    lds_barrier();                       // buf0 ready

    for (int t = 0; t < ntiles; t += 2) {
      // tile t: computers read buf0; we prep buf1 (set B) and store set A.
      if (t + 1 < ntiles) load_tile(t + 1, kvB, vvB, sB, oB);   // loads FIRST
      store_tile(kvA, vvA, sA, oA);                             // stores float
      if (t + 1 < ntiles) convert_tile(kvB, vvB, 1);            // counted vmcnt
      lds_barrier();
      // tile t+1: computers read buf1; we prep buf0 (set A) and store set B.
      if (t + 1 < ntiles) {
        if (t + 2 < ntiles) load_tile(t + 2, kvA, vvA, sA, oA);
        store_tile(kvB, vvB, sB, oB);
        if (t + 2 < ntiles) convert_tile(kvA, vvA, 0);
        lds_barrier();
      }
    }
    // loaders done; computers wrote O/ml.
  } else {
    // =========================== COMPUTER ===========================
    const int cw = w - 2;                // 0,1
    unsigned short* Pw = Plds[cw];

    s16x8 qf[2][4];
#pragma unroll
    for (int qs = 0; qs < 2; ++qs) {
      const unsigned short* qb = qws + ((size_t)bh * 64 + cw * 32 + qs * 16 + lr) * 128 + lg * 8;
#pragma unroll
      for (int kk = 0; kk < 4; ++kk) qf[qs][kk] = *(const s16x8*)(qb + kk * 32);
    }

    float mrow[2][4], lrow[2][4];
#pragma unroll
    for (int qs = 0; qs < 2; ++qs)
#pragma unroll
      for (int r = 0; r < 4; ++r) { mrow[qs][r] = -INFINITY; lrow[qs][r] = 0.f; }
    f32x4 Oacc[2][8] = {};

    lds_barrier();                       // wait buf0

    for (int t = 0; t < ntiles; ++t) {
      const unsigned short* Kb = Klds[t & 1];
      const unsigned short* Vb = VT[t & 1];

      f32x4 sc[2][2] = {};               // [qs][st]
#pragma unroll
      for (int kk = 0; kk < 4; ++kk)
#pragma unroll
        for (int st = 0; st < 2; ++st) {
          const int krow = st * 16 + lr;
          s16x8 kf = *(const s16x8*)(&Kb[krow * 128 + ((kk * 32 + lg * 8) ^ ((krow & 7) << 4))]);
#pragma unroll
          for (int qs = 0; qs < 2; ++qs)
            sc[qs][st] = MFMA_BF16(qf[qs][kk], kf, sc[qs][st]);
        }

#pragma unroll
      for (int qs = 0; qs < 2; ++qs)
#pragma unroll
        for (int r = 0; r < 4; ++r) {
          float tm = fmaxf(sc[qs][0][r], sc[qs][1][r]);
          tm = fmaxf(tm, __shfl_xor(tm, 1));
          tm = fmaxf(tm, __shfl_xor(tm, 2));
          tm = fmaxf(tm, __shfl_xor(tm, 4));
          tm = fmaxf(tm, __shfl_xor(tm, 8));
          const float mn = fmaxf(mrow[qs][r], tm);
          const float alpha = exp2f(mrow[qs][r] - mn);
          mrow[qs][r] = mn;
          const float p0f = exp2f(sc[qs][0][r] - mn);
          const float p1f = exp2f(sc[qs][1][r] - mn);
          float rs = p0f + p1f;
          rs += __shfl_xor(rs, 1);
          rs += __shfl_xor(rs, 2);
          rs += __shfl_xor(rs, 4);
          rs += __shfl_xor(rs, 8);
          lrow[qs][r] = lrow[qs][r] * alpha + rs;
#pragma unroll
          for (int dt = 0; dt < 8; ++dt) Oacc[qs][dt][r] *= alpha;
          const int prow = qs * 16 + lg * 4 + r;
          Pw[prow * 40 + lr] = f2bf(p0f);
          Pw[prow * 40 + 16 + lr] = f2bf(p1f);
        }

      s16x8 pf[2];
#pragma unroll
      for (int qs = 0; qs < 2; ++qs) {
        const s16x4 plo = *(const s16x4*)(&Pw[(qs * 16 + lr) * 40 + lg * 8]);
        const s16x4 phi = *(const s16x4*)(&Pw[(qs * 16 + lr) * 40 + lg * 8 + 4]);
        pf[qs] = __builtin_shufflevector(plo, phi, 0, 1, 2, 3, 4, 5, 6, 7);
      }
#pragma unroll
      for (int dt = 0; dt < 8; ++dt) {
        const int d = dt * 16 + lr;
        const s16x4 vlo = *(const s16x4*)(&Vb[d * 40 + lg * 8]);
        const s16x4 vhi = *(const s16x4*)(&Vb[d * 40 + lg * 8 + 4]);
        const s16x8 vf = __builtin_shufflevector(vlo, vhi, 0, 1, 2, 3, 4, 5, 6, 7);
#pragma unroll
        for (int qs = 0; qs < 2; ++qs)
          Oacc[qs][dt] = MFMA_BF16(pf[qs], vf, Oacc[qs][dt]);
      }
      lds_barrier();
    }

    const size_t rowbase = ((size_t)seg * 128 + bh) * 64 + cw * 32;
#pragma unroll
    for (int qs = 0; qs < 2; ++qs)
#pragma unroll
      for (int dt = 0; dt < 8; ++dt)
#pragma unroll
        for (int r = 0; r < 4; ++r)
          Ows[(rowbase + qs * 16 + lg * 4 + r) * 128 + dt * 16 + lr] = Oacc[qs][dt][r];
    if (lr == 0) {
#pragma unroll
      for (int qs = 0; qs < 2; ++qs)
#pragma unroll
        for (int r = 0; r < 4; ++r) {
          const size_t mi = rowbase + qs * 16 + lg * 4 + r;
          mlws[mi * 2 + 0] = mrow[qs][r];
          mlws[mi * 2 + 1] = lrow[qs][r];
        }
    }
  }
}

// ---------------------------------------------------------------------------
// Merge NSEG partials -> yhead (unrolled).
// ---------------------------------------------------------------------------
template <int NSEG>
__global__ __launch_bounds__(256) void combine_kernel(
    const float* __restrict__ Ows, const float* __restrict__ mlws,
    float* __restrict__ yhead)
{
  const int idx = blockIdx.x * 256 + threadIdx.x;
  const int d4 = (idx & 31) << 2;
  const int row = idx >> 5;
  float M = -INFINITY;
#pragma unroll
  for (int s = 0; s < NSEG; ++s) M = fmaxf(M, mlws[((size_t)s * 8192 + row) * 2]);
  f32x4 num = {0.f, 0.f, 0.f, 0.f};
  float den = 0.f;
#pragma unroll
  for (int s = 0; s < NSEG; ++s) {
    const size_t r = (size_t)s * 8192 + row;
    const float wgt = exp2f(mlws[r * 2] - M);
    den += wgt * mlws[r * 2 + 1];
    const f32x4 o4 = *(const f32x4*)(Ows + r * 128 + d4);
#pragma unroll
    for (int e = 0; e < 4; ++e) num[e] += wgt * o4[e];
  }
  const float inv = 1.0f / den;
  const int bh = row >> 6, q = row & 63;
  const int b = bh >> 4, h = bh & 15;
  float* yp = yhead + (size_t)(b * 64 + q) * 2048 + h * 128 + d4;
#pragma unroll
  for (int e = 0; e < 4; ++e) yp[e] = num[e] * inv;
}

// ---------------------------------------------------------------------------
extern "C" void kernel_launch(void* const* d_in, const int* in_sizes, int n_in,
                              void* d_out, int out_size, void* d_ws, size_t ws_size,
                              hipStream_t stream)
{
  (void)in_sizes; (void)n_in; (void)out_size;
  const float* x  = (const float*)d_in[0];
  const float* pk = (const float*)d_in[1];
  const float* pv = (const float*)d_in[2];
  const float* wa = (const float*)d_in[3];
  const float* wp = (const float*)d_in[4];

  float* out  = (float*)d_out;
  float* y    = out;                          // 1,048,576
  float* kout = out + 1048576;                // 68,157,440
  float* vout = out + 1048576 + 68157440;     // 68,157,440

  char* ws = (char*)d_ws;
  unsigned short* qws = (unsigned short*)(ws);                      // 2 MiB bf16
  float* yhead = (float*)(ws + ((size_t)2 << 20));                  // 4 MiB f32
  float* mlws  = (float*)(ws + ((size_t)6 << 20));                  // <=852 KiB
  float* Ows   = (float*)(ws + ((size_t)7 << 20));                  // nseg*4 MiB

  const size_t base = (size_t)7 << 20;
  int nseg = 1;
  if (ws_size >= base + (size_t)13 * 4194304) nseg = 13;     // 1664 blocks
  else if (ws_size >= base + (size_t)5 * 4194304) nseg = 5;
  const int seglen = 4160 / nseg;   // 320 / 832 / 4160 -> ntiles 10/26/130 (even)
  const int ntiles = seglen / 32;

  gemm_kernel<64><<<dim3(48, 8), dim3(256), 0, stream>>>(x, wa, 6144, 0, qws, kout, vout, nullptr);
  attn_kernel<<<dim3(128 * nseg), dim3(256), 0, stream>>>(pk, pv, qws, kout, vout, Ows, mlws,
                                                          nseg, seglen, ntiles);
  if (nseg == 13)      combine_kernel<13><<<dim3(1024), dim3(256), 0, stream>>>(Ows, mlws, yhead);
  else if (nseg == 5)  combine_kernel<5><<<dim3(1024), dim3(256), 0, stream>>>(Ows, mlws, yhead);
  else                 combine_kernel<1><<<dim3(1024), dim3(256), 0, stream>>>(Ows, mlws, yhead);
  gemm_kernel<32><<<dim3(16, 16), dim3(256), 0, stream>>>(yhead, wp, 2048, 1, nullptr, nullptr, nullptr, y);
}

// Round 15
// 339.304 us; speedup vs baseline: 1.0008x; 1.0008x over previous
//
#include <hip/hip_runtime.h>
#include <math.h>

// CausalSelfAttention w/ KV cache, MI355X gfx950.
// B=8 T=64 C=2048 H=16 hd=128 S=4096 -> SKV=4160. All device I/O is FLOAT32.
// Internals: bf16 MFMA (16x16x32), f32 accumulate.
// R13: WAVE-SPECIALIZED attn (producer-consumer). Waves 0-1 = loaders:
// stream K/V tiles (2 reg sets, loads-before-stores), write bf16 into
// double-buffered LDS + f32 cache-copy stores; they never sit in the compute
// chain. Waves 2-3 = computers (32 q each): QK/softmax/PV from LDS only.
// ONE lgkm-only barrier per tile (dbuf handoff). 3 blocks/CU.
// gemm = R5 depth-1 (best-known 344 config). nseg=13.

typedef __attribute__((ext_vector_type(4))) float f32x4;
typedef __attribute__((ext_vector_type(8))) short s16x8;
typedef __attribute__((ext_vector_type(4))) short s16x4;
typedef __attribute__((ext_vector_type(2))) unsigned int u32x2;
typedef __attribute__((ext_vector_type(4))) unsigned int u32x4;

#define MFMA_BF16(A_, B_, C_) __builtin_amdgcn_mfma_f32_16x16x32_bf16((A_), (B_), (C_), 0, 0, 0)

__device__ __forceinline__ unsigned short f2bf(float f) {
  unsigned int u = __builtin_bit_cast(unsigned int, f);
  u += 0x7FFFu + ((u >> 16) & 1u);
  return (unsigned short)(u >> 16);
}
__device__ __forceinline__ unsigned int pack2(float a, float b) {
  return (unsigned int)f2bf(a) | ((unsigned int)f2bf(b) << 16);
}
// Barrier with LDS-visibility only: does NOT drain vmcnt (loader stores/loads
// stay in flight across tiles).
__device__ __forceinline__ void lds_barrier() {
  asm volatile("s_waitcnt lgkmcnt(0)" ::: "memory");
  __builtin_amdgcn_s_barrier();
}

// ---------------------------------------------------------------------------
// GEMM (R5 depth-1, best-known). BM x 128 tile, 4 waves (2x2), k-step 64.
// mode 0 (qkv, BM=64): n<2048 -> qws (bf16*QSCALE, [B,H,T,hd]); 2048..4095 ->
// kout tail rows 4096..4159; >=4096 -> vout tail. mode 1 (proj, BM=32).
// ---------------------------------------------------------------------------
constexpr float QSCALE = 0.08838834764831845f * 1.4426950408889634f; // 1/sqrt(128)*log2e

template <int BM>
__global__ __launch_bounds__(256) void gemm_kernel(
    const float* __restrict__ A, const float* __restrict__ W,
    int ncols, int mode,
    unsigned short* __restrict__ qws, float* __restrict__ kout,
    float* __restrict__ vout, float* __restrict__ yout)
{
  constexpr int MI = BM / 32;
  constexpr int AIT = BM / 32;
  __shared__ __align__(16) unsigned short Alds[BM][72];
  __shared__ __align__(16) unsigned short Blds[128][72];

  const int tid = threadIdx.x;
  const int w = tid >> 6, l = tid & 63;
  const int lr = l & 15, lg = l >> 4;
  const int n0 = blockIdx.x * 128;
  const int m0 = blockIdx.y * BM;
  const int wm = (w >> 1) * (BM / 2), wn = (w & 1) * 64;

  const int arow = tid >> 3, acol = (tid & 7) << 3;
  const int bkp = tid >> 4, bcol = (tid & 15) << 3;
  const int bswz = ((bcol >> 3) & 7) << 3;

  f32x4 ar[AIT][2];
  f32x4 br[2][4];

  auto loadA = [&](int k0) {
#pragma unroll
    for (int it = 0; it < AIT; ++it) {
      const float* pa = A + (size_t)(m0 + it * 32 + arow) * 2048 + k0 + acol;
      ar[it][0] = *(const f32x4*)pa;
      ar[it][1] = *(const f32x4*)(pa + 4);
    }
  };
  auto loadB = [&](int k0) {
#pragma unroll
    for (int i = 0; i < 2; ++i) {
      const int krow = 2 * (i * 16 + bkp);
      const float* pw = W + (size_t)(k0 + krow) * ncols + n0 + bcol;
      br[i][0] = *(const f32x4*)pw;
      br[i][1] = *(const f32x4*)(pw + 4);
      br[i][2] = *(const f32x4*)(pw + ncols);
      br[i][3] = *(const f32x4*)(pw + ncols + 4);
    }
  };

  f32x4 acc[MI][4] = {};

  loadA(0); loadB(0);
  for (int ks = 0; ks < 32; ++ks) {
#pragma unroll
    for (int it = 0; it < AIT; ++it) {
      u32x4 p;
      p[0] = pack2(ar[it][0][0], ar[it][0][1]); p[1] = pack2(ar[it][0][2], ar[it][0][3]);
      p[2] = pack2(ar[it][1][0], ar[it][1][1]); p[3] = pack2(ar[it][1][2], ar[it][1][3]);
      *(u32x4*)(&Alds[it * 32 + arow][acol]) = p;
    }
#pragma unroll
    for (int i = 0; i < 2; ++i) {
      const int krow = 2 * (i * 16 + bkp);
      const int kc = krow ^ bswz;
#pragma unroll
      for (int j = 0; j < 8; ++j) {
        const float v0 = (j < 4) ? br[i][0][j] : br[i][1][j - 4];
        const float v1 = (j < 4) ? br[i][2][j] : br[i][3][j - 4];
        *(unsigned int*)(&Blds[bcol + j][kc]) = pack2(v0, v1);
      }
    }
    lds_barrier();

    if (ks < 31) { loadA((ks + 1) * 64); loadB((ks + 1) * 64); }

    s16x8 af[MI][2], bfr[4][2];
#pragma unroll
    for (int mi = 0; mi < MI; ++mi)
#pragma unroll
      for (int kk = 0; kk < 2; ++kk)
        af[mi][kk] = *(const s16x8*)(&Alds[wm + mi * 16 + lr][kk * 32 + lg * 8]);
#pragma unroll
    for (int ni = 0; ni < 4; ++ni) {
      const int n = wn + ni * 16 + lr;
      const int nswz = ((n >> 3) & 7) << 3;
#pragma unroll
      for (int kk = 0; kk < 2; ++kk)
        bfr[ni][kk] = *(const s16x8*)(&Blds[n][(kk * 32 + lg * 8) ^ nswz]);
    }
#pragma unroll
    for (int kk = 0; kk < 2; ++kk)
#pragma unroll
      for (int mi = 0; mi < MI; ++mi)
#pragma unroll
        for (int ni = 0; ni < 4; ++ni)
          acc[mi][ni] = MFMA_BF16(af[mi][kk], bfr[ni][kk], acc[mi][ni]);
    lds_barrier();
  }

  if (mode == 0) {
    const int which = n0 >> 11;
    const int h = (n0 >> 7) & 15;
    float* kv = (which == 1) ? kout : vout;
#pragma unroll
    for (int mi = 0; mi < MI; ++mi)
#pragma unroll
      for (int ni = 0; ni < 4; ++ni) {
        const int d = wn + ni * 16 + lr;
#pragma unroll
        for (int r = 0; r < 4; ++r) {
          const int mg = m0 + wm + mi * 16 + lg * 4 + r;
          const int b = mg >> 6, t = mg & 63;
          const float val = acc[mi][ni][r];
          if (which == 0)
            qws[(((size_t)(b * 16 + h) * 64 + t) << 7) + d] = f2bf(val * QSCALE);
          else
            kv[((size_t)(b * 16 + h) * 4160 + 4096 + t) * 128 + d] = val;
        }
      }
  } else {
#pragma unroll
    for (int mi = 0; mi < MI; ++mi)
#pragma unroll
      for (int ni = 0; ni < 4; ++ni) {
        const int n = n0 + wn + ni * 16 + lr;
#pragma unroll
        for (int r = 0; r < 4; ++r) {
          const int mg = m0 + wm + mi * 16 + lg * 4 + r;
          yout[(size_t)mg * 2048 + n] = acc[mi][ni][r];
        }
      }
  }
}

// ---------------------------------------------------------------------------
// Wave-specialized fused cache-copy + flash attention.
// Waves 0-1: loaders (128 threads): thread owns key-row skr=tid>>2, float cols
//   sd+16c (64B/row/instr coalesced). 2 reg sets; per tile: issue loads(t+1)
//   FIRST, then copy-stores(t), then convert(t+1)->LDS (counted vmcnt).
// Waves 2-3: computers, 32 q-rows each, LDS-only inner loop.
// LDS (dbuf): K[2][32][128] full-row-XOR; VT[2][128][40]; P[2 cw][32][40].
// One lds_barrier per tile. ntiles must be EVEN (130/26/10 all even).
// ---------------------------------------------------------------------------
__global__ __launch_bounds__(256) void attn_kernel(
    const float* __restrict__ pastk, const float* __restrict__ pastv,
    const unsigned short* __restrict__ qws,
    float* __restrict__ kout, float* __restrict__ vout,
    float* __restrict__ Ows, float* __restrict__ mlws,
    int nseg, int seglen, int ntiles)
{
  __shared__ __align__(16) unsigned short Klds[2][32 * 128];
  __shared__ __align__(16) unsigned short VT[2][128 * 40];
  __shared__ __align__(16) unsigned short Plds[2][32 * 40];

  const int tid = threadIdx.x;
  const int w = tid >> 6, l = tid & 63;
  const int lr = l & 15, lg = l >> 4;
  const int bh = blockIdx.x / nseg;
  const int seg = blockIdx.x % nseg;
  const int segbase = seg * seglen;

  if (w < 2) {
    // ============================ LOADER ============================
    const int skr = tid >> 2;          // key row 0..31
    const int sd = (tid & 3) << 2;     // float col start 0,4,8,12
    const int kswz = (skr & 7) << 4;   // full-row XOR (ushort units)

    f32x4 kvA[8], vvA[8], kvB[8], vvB[8];
    int sA = 0, sB = 0; size_t oA = 0, oB = 0;

    auto load_tile = [&](int t, f32x4 (&kv)[8], f32x4 (&vv)[8], int& sr, size_t& oor) {
      const int s = segbase + t * 32 + skr;
      const size_t oo = ((size_t)bh * 4160 + s) * 128 + sd;
      sr = s; oor = oo;
      if (s < 4096) {
        const float* a = pastk + ((size_t)bh * 4096 + s) * 128 + sd;
        const float* b = pastv + ((size_t)bh * 4096 + s) * 128 + sd;
#pragma unroll
        for (int c = 0; c < 8; ++c) { kv[c] = *(const f32x4*)(a + 16 * c); vv[c] = *(const f32x4*)(b + 16 * c); }
      } else {
#pragma unroll
        for (int c = 0; c < 8; ++c) { kv[c] = *(const f32x4*)(kout + oo + 16 * c); vv[c] = *(const f32x4*)(vout + oo + 16 * c); }
      }
    };
    auto store_tile = [&](const f32x4 (&kv)[8], const f32x4 (&vv)[8], int sr, size_t oo) {
      if (sr < 4096) {
        float* ko = kout + oo; float* vo = vout + oo;
#pragma unroll
        for (int c = 0; c < 8; ++c) { *(f32x4*)(ko + 16 * c) = kv[c]; *(f32x4*)(vo + 16 * c) = vv[c]; }
      }
    };
    auto convert_tile = [&](const f32x4 (&kv)[8], const f32x4 (&vv)[8], int buf) {
      unsigned short* Kb = Klds[buf];
      unsigned short* Vb = VT[buf];
#pragma unroll
      for (int c = 0; c < 8; ++c) {
        const int d0 = sd + 16 * c;
        u32x2 pk;
        pk[0] = pack2(kv[c][0], kv[c][1]);
        pk[1] = pack2(kv[c][2], kv[c][3]);
        *(u32x2*)(&Kb[skr * 128 + (d0 ^ kswz)]) = pk;
#pragma unroll
        for (int e = 0; e < 4; ++e)
          Vb[(d0 + e) * 40 + skr] = f2bf(vv[c][e]);
      }
    };

    load_tile(0, kvA, vvA, sA, oA);
    convert_tile(kvA, vvA, 0);
    lds_barrier();                       // buf0 ready

    for (int t = 0; t < ntiles; t += 2) {
      // tile t: computers read buf0; we prep buf1 (set B) and store set A.
      if (t + 1 < ntiles) load_tile(t + 1, kvB, vvB, sB, oB);   // loads FIRST
      store_tile(kvA, vvA, sA, oA);                             // stores float
      if (t + 1 < ntiles) convert_tile(kvB, vvB, 1);            // counted vmcnt
      lds_barrier();
      // tile t+1: computers read buf1; we prep buf0 (set A) and store set B.
      if (t + 1 < ntiles) {
        if (t + 2 < ntiles) load_tile(t + 2, kvA, vvA, sA, oA);
        store_tile(kvB, vvB, sB, oB);
        if (t + 2 < ntiles) convert_tile(kvA, vvA, 0);
        lds_barrier();
      }
    }
    // loaders done; computers wrote O/ml.
  } else {
    // =========================== COMPUTER ===========================
    const int cw = w - 2;                // 0,1
    unsigned short* Pw = Plds[cw];

    s16x8 qf[2][4];
#pragma unroll
    for (int qs = 0; qs < 2; ++qs) {
      const unsigned short* qb = qws + ((size_t)bh * 64 + cw * 32 + qs * 16 + lr) * 128 + lg * 8;
#pragma unroll
      for (int kk = 0; kk < 4; ++kk) qf[qs][kk] = *(const s16x8*)(qb + kk * 32);
    }

    float mrow[2][4], lrow[2][4];
#pragma unroll
    for (int qs = 0; qs < 2; ++qs)
#pragma unroll
      for (int r = 0; r < 4; ++r) { mrow[qs][r] = -INFINITY; lrow[qs][r] = 0.f; }
    f32x4 Oacc[2][8] = {};

    lds_barrier();                       // wait buf0

    for (int t = 0; t < ntiles; ++t) {
      const unsigned short* Kb = Klds[t & 1];
      const unsigned short* Vb = VT[t & 1];

      f32x4 sc[2][2] = {};               // [qs][st]
#pragma unroll
      for (int kk = 0; kk < 4; ++kk)
#pragma unroll
        for (int st = 0; st < 2; ++st) {
          const int krow = st * 16 + lr;
          s16x8 kf = *(const s16x8*)(&Kb[krow * 128 + ((kk * 32 + lg * 8) ^ ((krow & 7) << 4))]);
#pragma unroll
          for (int qs = 0; qs < 2; ++qs)
            sc[qs][st] = MFMA_BF16(qf[qs][kk], kf, sc[qs][st]);
        }

#pragma unroll
      for (int qs = 0; qs < 2; ++qs)
#pragma unroll
        for (int r = 0; r < 4; ++r) {
          float tm = fmaxf(sc[qs][0][r], sc[qs][1][r]);
          tm = fmaxf(tm, __shfl_xor(tm, 1));
          tm = fmaxf(tm, __shfl_xor(tm, 2));
          tm = fmaxf(tm, __shfl_xor(tm, 4));
          tm = fmaxf(tm, __shfl_xor(tm, 8));
          const float mn = fmaxf(mrow[qs][r], tm);
          const float alpha = exp2f(mrow[qs][r] - mn);
          mrow[qs][r] = mn;
          const float p0f = exp2f(sc[qs][0][r] - mn);
          const float p1f = exp2f(sc[qs][1][r] - mn);
          float rs = p0f + p1f;
          rs += __shfl_xor(rs, 1);
          rs += __shfl_xor(rs, 2);
          rs += __shfl_xor(rs, 4);
          rs += __shfl_xor(rs, 8);
          lrow[qs][r] = lrow[qs][r] * alpha + rs;
#pragma unroll
          for (int dt = 0; dt < 8; ++dt) Oacc[qs][dt][r] *= alpha;
          const int prow = qs * 16 + lg * 4 + r;
          Pw[prow * 40 + lr] = f2bf(p0f);
          Pw[prow * 40 + 16 + lr] = f2bf(p1f);
        }

      s16x8 pf[2];
#pragma unroll
      for (int qs = 0; qs < 2; ++qs) {
        const s16x4 plo = *(const s16x4*)(&Pw[(qs * 16 + lr) * 40 + lg * 8]);
        const s16x4 phi = *(const s16x4*)(&Pw[(qs * 16 + lr) * 40 + lg * 8 + 4]);
        pf[qs] = __builtin_shufflevector(plo, phi, 0, 1, 2, 3, 4, 5, 6, 7);
      }
#pragma unroll
      for (int dt = 0; dt < 8; ++dt) {
        const int d = dt * 16 + lr;
        const s16x4 vlo = *(const s16x4*)(&Vb[d * 40 + lg * 8]);
        const s16x4 vhi = *(const s16x4*)(&Vb[d * 40 + lg * 8 + 4]);
        const s16x8 vf = __builtin_shufflevector(vlo, vhi, 0, 1, 2, 3, 4, 5, 6, 7);
#pragma unroll
        for (int qs = 0; qs < 2; ++qs)
          Oacc[qs][dt] = MFMA_BF16(pf[qs], vf, Oacc[qs][dt]);
      }
      lds_barrier();
    }

    const size_t rowbase = ((size_t)seg * 128 + bh) * 64 + cw * 32;
#pragma unroll
    for (int qs = 0; qs < 2; ++qs)
#pragma unroll
      for (int dt = 0; dt < 8; ++dt)
#pragma unroll
        for (int r = 0; r < 4; ++r)
          Ows[(rowbase + qs * 16 + lg * 4 + r) * 128 + dt * 16 + lr] = Oacc[qs][dt][r];
    if (lr == 0) {
#pragma unroll
      for (int qs = 0; qs < 2; ++qs)
#pragma unroll
        for (int r = 0; r < 4; ++r) {
          const size_t mi = rowbase + qs * 16 + lg * 4 + r;
          mlws[mi * 2 + 0] = mrow[qs][r];
          mlws[mi * 2 + 1] = lrow[qs][r];
        }
    }
  }
}

// ---------------------------------------------------------------------------
// Merge NSEG partials -> yhead (unrolled).
// ---------------------------------------------------------------------------
template <int NSEG>
__global__ __launch_bounds__(256) void combine_kernel(
    const float* __restrict__ Ows, const float* __restrict__ mlws,
    float* __restrict__ yhead)
{
  const int idx = blockIdx.x * 256 + threadIdx.x;
  const int d4 = (idx & 31) << 2;
  const int row = idx >> 5;
  float M = -INFINITY;
#pragma unroll
  for (int s = 0; s < NSEG; ++s) M = fmaxf(M, mlws[((size_t)s * 8192 + row) * 2]);
  f32x4 num = {0.f, 0.f, 0.f, 0.f};
  float den = 0.f;
#pragma unroll
  for (int s = 0; s < NSEG; ++s) {
    const size_t r = (size_t)s * 8192 + row;
    const float wgt = exp2f(mlws[r * 2] - M);
    den += wgt * mlws[r * 2 + 1];
    const f32x4 o4 = *(const f32x4*)(Ows + r * 128 + d4);
#pragma unroll
    for (int e = 0; e < 4; ++e) num[e] += wgt * o4[e];
  }
  const float inv = 1.0f / den;
  const int bh = row >> 6, q = row & 63;
  const int b = bh >> 4, h = bh & 15;
  float* yp = yhead + (size_t)(b * 64 + q) * 2048 + h * 128 + d4;
#pragma unroll
  for (int e = 0; e < 4; ++e) yp[e] = num[e] * inv;
}

// ---------------------------------------------------------------------------
extern "C" void kernel_launch(void* const* d_in, const int* in_sizes, int n_in,
                              void* d_out, int out_size, void* d_ws, size_t ws_size,
                              hipStream_t stream)
{
  (void)in_sizes; (void)n_in; (void)out_size;
  const float* x  = (const float*)d_in[0];
  const float* pk = (const float*)d_in[1];
  const float* pv = (const float*)d_in[2];
  const float* wa = (const float*)d_in[3];
  const float* wp = (const float*)d_in[4];

  float* out  = (float*)d_out;
  float* y    = out;                          // 1,048,576
  float* kout = out + 1048576;                // 68,157,440
  float* vout = out + 1048576 + 68157440;     // 68,157,440

  char* ws = (char*)d_ws;
  unsigned short* qws = (unsigned short*)(ws);                      // 2 MiB bf16
  float* yhead = (float*)(ws + ((size_t)2 << 20));                  // 4 MiB f32
  float* mlws  = (float*)(ws + ((size_t)6 << 20));                  // <=852 KiB
  float* Ows   = (float*)(ws + ((size_t)7 << 20));                  // nseg*4 MiB

  const size_t base = (size_t)7 << 20;
  int nseg = 1;
  if (ws_size >= base + (size_t)13 * 4194304) nseg = 13;     // 1664 blocks
  else if (ws_size >= base + (size_t)5 * 4194304) nseg = 5;
  const int seglen = 4160 / nseg;   // 320 / 832 / 4160 -> ntiles 10/26/130 (even)
  const int ntiles = seglen / 32;

  gemm_kernel<64><<<dim3(48, 8), dim3(256), 0, stream>>>(x, wa, 6144, 0, qws, kout, vout, nullptr);
  attn_kernel<<<dim3(128 * nseg), dim3(256), 0, stream>>>(pk, pv, qws, kout, vout, Ows, mlws,
                                                          nseg, seglen, ntiles);
  if (nseg == 13)      combine_kernel<13><<<dim3(1024), dim3(256), 0, stream>>>(Ows, mlws, yhead);
  else if (nseg == 5)  combine_kernel<5><<<dim3(1024), dim3(256), 0, stream>>>(Ows, mlws, yhead);
  else                 combine_kernel<1><<<dim3(1024), dim3(256), 0, stream>>>(Ows, mlws, yhead);
  gemm_kernel<32><<<dim3(16, 16), dim3(256), 0, stream>>>(yhead, wp, 2048, 1, nullptr, nullptr, nullptr, y);
}